// Round 3
// baseline (2430.802 us; speedup 1.0000x reference)
//
#include <hip/hip_runtime.h>
#include <cfloat>
#include <climits>
#include <math.h>

// Problem constants (fixed by reference)
#define BB 2048
#define NN 50000
#define DD 128
#define KK 20

// K1 tiling
#define NSLICE 10
#define NSL 5000        // NN / NSLICE
#define NC 40           // book rows staged per chunk
#define NCHUNK 125      // NSL / NC
#define TILEB 64        // rows per block
#define GG 8            // n-partitions per row per slice
#define NT 5            // NC / GG
#define LL 12           // per-thread candidate list length
#define SL 12           // per-(row,slice) survivors after in-wave merge
#define CAND (NSLICE*SL)  // 120 candidates per row per task

// out layout (floats): vals_cos, ind_cos, labels_rot, vals_euc, ind_euc, labels_trans
#define O_VC 0
#define O_IC 40960
#define O_LR 81920
#define O_VE 122880
#define O_IE 163840
#define O_LT 204800

// ---------------- K0: bq[n] = ||trans_book[n]||^2 (fp32, selection only) ------------
__global__ __launch_bounds__(256) void k0_bq(const float* __restrict__ Bt,
                                             float* __restrict__ bq) {
    int gid = blockIdx.x * 256 + threadIdx.x;
    int row = gid >> 5;
    int lane = threadIdx.x & 31;
    if (row < NN) {
        float4 v = *reinterpret_cast<const float4*>(Bt + (size_t)row * DD + lane * 4);
        float s = v.x * v.x + v.y * v.y + v.z * v.z + v.w * v.w;
        #pragma unroll
        for (int m = 1; m < 32; m <<= 1) s += __shfl_xor(s, m, 64);
        if (lane == 0) bq[row] = s;
    }
}

// ---------------- K1: fp32 scoring + per-(row,slice) top-SL candidate indices -------
__global__ __launch_bounds__(256) void k1_score(
    const float* __restrict__ Zr, const float* __restrict__ Zt,
    const float* __restrict__ Br, const float* __restrict__ Bt,
    const float* __restrict__ bq,
    int* __restrict__ candI)
{
    const int slice = blockIdx.x;   // 0..9
    const int tile  = blockIdx.y;   // 0..31
    const int task  = blockIdx.z;   // 0 = cos, 1 = euc
    const float* __restrict__ Z  = task ? Zt : Zr;
    const float* __restrict__ Bk = task ? Bt : Br;

    __shared__ __align__(16) float z_lds[TILEB][132];  // +4 pad breaks bank aliasing
    __shared__ __align__(16) float b_lds[NC][132];
    __shared__ float bq_lds[NC];

    const int t = threadIdx.x;
    const int r0 = tile * TILEB;
    const int nbase = slice * NSL;

    // stage z tile (64 x 128 floats)
    #pragma unroll
    for (int i = 0; i < 8; i++) {
        int idx = t + i * 256;
        int r = idx >> 5, kq = idx & 31;
        float4 v = *reinterpret_cast<const float4*>(Z + (size_t)(r0 + r) * DD + kq * 4);
        *reinterpret_cast<float4*>(&z_lds[r][kq * 4]) = v;
    }

    const int rp = t >> 3;         // 0..31 -> rows {2rp, 2rp+1}
    const int g  = t & 7;          // n-partition within slice
    const int rA = rp * 2;

    float ls[2][LL]; int li[2][LL];
    float lmin[2]; int mpos[2];
    #pragma unroll
    for (int rr = 0; rr < 2; rr++) {
        #pragma unroll
        for (int u = 0; u < LL; u++) { ls[rr][u] = -FLT_MAX; li[rr][u] = INT_MAX; }
        lmin[rr] = -FLT_MAX; mpos[rr] = 0;
    }
    const bool is_euc = (task != 0);

    for (int c = 0; c < NCHUNK; c++) {
        const int n0 = nbase + c * NC;
        __syncthreads();   // protect LDS from previous iteration's readers
        #pragma unroll
        for (int i = 0; i < 5; i++) {
            int idx = t + i * 256;
            int nl = idx >> 5, kq = idx & 31;
            float4 v = *reinterpret_cast<const float4*>(Bk + (size_t)(n0 + nl) * DD + kq * 4);
            *reinterpret_cast<float4*>(&b_lds[nl][kq * 4]) = v;
        }
        if (t < NC) bq_lds[t] = bq[n0 + t];
        __syncthreads();

        float acc[2][NT];
        #pragma unroll
        for (int rr = 0; rr < 2; rr++)
            #pragma unroll
            for (int j = 0; j < NT; j++) acc[rr][j] = 0.f;

        for (int kq = 0; kq < 32; kq++) {
            float4 za = *reinterpret_cast<const float4*>(&z_lds[rA][kq * 4]);
            float4 zb = *reinterpret_cast<const float4*>(&z_lds[rA + 1][kq * 4]);
            #pragma unroll
            for (int j = 0; j < NT; j++) {
                float4 b4 = *reinterpret_cast<const float4*>(&b_lds[g + (j << 3)][kq * 4]);
                acc[0][j] += za.x * b4.x + za.y * b4.y + za.z * b4.z + za.w * b4.w;
                acc[1][j] += zb.x * b4.x + zb.y * b4.y + zb.z * b4.z + zb.w * b4.w;
            }
        }

        #pragma unroll
        for (int j = 0; j < NT; j++) {
            const int nl = g + (j << 3);
            const float bqv = bq_lds[nl];
            const int n = n0 + nl;
            #pragma unroll
            for (int rr = 0; rr < 2; rr++) {
                float s = is_euc ? (2.f * acc[rr][j] - bqv) : acc[rr][j];
                if (s > lmin[rr]) {
                    #pragma unroll
                    for (int u = 0; u < LL; u++)
                        if (u == mpos[rr]) { ls[rr][u] = s; li[rr][u] = n; }
                    float m = ls[rr][0]; int mp = 0;
                    #pragma unroll
                    for (int u = 1; u < LL; u++)
                        if (ls[rr][u] < m) { m = ls[rr][u]; mp = u; }
                    lmin[rr] = m; mpos[rr] = mp;
                }
            }
        }
    }

    // In-wave merge: 8 contiguous lanes per row-pair tournament-select top-SL
    // of their 8x12 lists. Writes candidate INDICES only (~2 MB total ws).
    #pragma unroll
    for (int rr = 0; rr < 2; rr++) {
        const int row = r0 + rA + rr;
        const int base = ((task * BB + row) * NSLICE + slice) * SL;
        for (int rd = 0; rd < SL; rd++) {
            float bs = -FLT_MAX; int bn = INT_MAX; int bq_ = -1;
            #pragma unroll
            for (int u = 0; u < LL; u++)
                if (ls[rr][u] > bs || (ls[rr][u] == bs && li[rr][u] < bn)) {
                    bs = ls[rr][u]; bn = li[rr][u]; bq_ = u;
                }
            const float ms = bs; const int mn = bn;
            #pragma unroll
            for (int m = 1; m < GG; m <<= 1) {
                float os = __shfl_xor(bs, m, 64);
                int on = __shfl_xor(bn, m, 64);
                if (os > bs || (os == bs && on < bn)) { bs = os; bn = on; }
            }
            if (bs == ms && bn == mn) {   // this lane won: pop its entry
                #pragma unroll
                for (int u = 0; u < LL; u++) if (u == bq_) ls[rr][u] = -FLT_MAX;
            }
            if (g == 0) candI[base + rd] = bn;
        }
    }
}

// ---------------- K2: final ranking + gather ----------------------------------------
// cos (task 0): exact fp64 rescore + top-20 (passed in R2 — unchanged).
// euc (task 1): bit-exact emulation of numpy fp32 semantics:
//   dot  = np.einsum contig_two SSE path: 4 lane accs (d mod 4), mul+add (no FMA),
//          reduced (L0+L2)+(L1+L3)
//   zq,bq= np pairwise_sum of x*x: 8 accs (d mod 8), ((r0+r1)+(r2+r3))+((r4+r5)+(r6+r7))
//   s    = ((2.0f*dot) - zq) - bq, left-to-right
//   rank = stable top-k (ties -> lower index)
__global__ __launch_bounds__(256) void k2_final(
    const float* __restrict__ Zr, const float* __restrict__ Zt,
    const float* __restrict__ Br, const float* __restrict__ Bt,
    const float* __restrict__ rotB, const float* __restrict__ transB,
    const int* __restrict__ candI,
    float* __restrict__ out)
{
    const int row = blockIdx.x;
    const int task = blockIdx.y;
    const int t = threadIdx.x;
    const float* __restrict__ Z  = task ? Zt : Zr;
    const float* __restrict__ Bk = task ? Bt : Br;

    __shared__ __align__(16) float zrow[DD];
    __shared__ int sel[CAND];
    __shared__ double dotp[CAND * 8];
    __shared__ double bbp[CAND * 8];
    __shared__ double sval[KK];
    __shared__ int sidx[KK];
    __shared__ float sv[CAND];

    if (t < DD) zrow[t] = Z[(size_t)row * DD + t];
    if (t < CAND) sel[t] = candI[((size_t)task * BB + row) * CAND + t];
    __syncthreads();

    if (task == 0) {
        // ---------------- cos: exact fp64 (unchanged from R2; passes) --------------
        #pragma unroll
        for (int it = 0; it < 4; it++) {
            int idx = t + it * 256;
            if (idx < CAND * 8) {
                int cnd = idx >> 3, part = idx & 7;
                int n = sel[cnd];
                const float* brow = Bk + (size_t)n * DD + part * 16;
                double dp = 0.0;
                #pragma unroll
                for (int q = 0; q < 4; q++) {
                    float4 b4 = *reinterpret_cast<const float4*>(brow + q * 4);
                    const int k = part * 16 + q * 4;
                    dp += (double)zrow[k + 0] * (double)b4.x + (double)zrow[k + 1] * (double)b4.y
                        + (double)zrow[k + 2] * (double)b4.z + (double)zrow[k + 3] * (double)b4.w;
                }
                dotp[idx] = dp;
            }
        }
        __syncthreads();

        if (t < 64) {
            double zq = (double)zrow[t] * (double)zrow[t]
                      + (double)zrow[t + 64] * (double)zrow[t + 64];
            #pragma unroll
            for (int m = 1; m < 64; m <<= 1) zq += __shfl_xor(zq, m, 64);

            double s0, s1 = -DBL_MAX; int i0, i1 = INT_MAX;
            {
                double dot = 0.0;
                #pragma unroll
                for (int p = 0; p < 8; p++) dot += dotp[t * 8 + p];
                i0 = sel[t]; s0 = dot;
            }
            if (t + 64 < CAND) {
                double dot = 0.0;
                #pragma unroll
                for (int p = 0; p < 8; p++) dot += dotp[(t + 64) * 8 + p];
                i1 = sel[t + 64]; s1 = dot;
            }

            for (int rd = 0; rd < KK; rd++) {
                double bs; int bn;
                if (s0 > s1 || (s0 == s1 && i0 < i1)) { bs = s0; bn = i0; }
                else                                  { bs = s1; bn = i1; }
                const double ms = bs; const int mn = bn;
                #pragma unroll
                for (int m = 1; m < 64; m <<= 1) {
                    double os = __shfl_xor(bs, m, 64);
                    int on = __shfl_xor(bn, m, 64);
                    if (os > bs || (os == bs && on < bn)) { bs = os; bn = on; }
                }
                if (bs == ms && bn == mn) {
                    if (i0 == mn) s0 = -DBL_MAX; else s1 = -DBL_MAX;
                }
                if (t == 0) { sval[rd] = bs; sidx[rd] = bn; }
            }
            if (t == 0) dotp[0] = zq;
        }
        __syncthreads();

        if (t < KK) {
            const double zq = dotp[0];
            const int n = sidx[t];
            const int o = row * KK + t;
            out[O_VC + o] = (float)(sval[t] / sqrt(zq));
            out[O_IC + o] = (float)n;
            out[O_LR + o] = rotB[n];
        }
    } else {
        // ---------------- euc: bit-exact numpy-fp32 emulation ----------------------
        if (t < CAND) {
            const int n = sel[t];
            const float* brow = Bk + (size_t)n * DD;
            float L[4], r[8], q[8];
            #pragma unroll
            for (int u = 0; u < 4; u++) L[u] = 0.f;
            #pragma unroll
            for (int u = 0; u < 8; u++) { r[u] = 0.f; q[u] = 0.f; }
            #pragma unroll
            for (int c4 = 0; c4 < 32; c4++) {
                float4 b4 = *reinterpret_cast<const float4*>(brow + c4 * 4);
                float4 z4 = *reinterpret_cast<const float4*>(&zrow[c4 * 4]);
                const int m8 = (c4 & 1) * 4;
                L[0] = __fadd_rn(L[0], __fmul_rn(z4.x, b4.x));
                L[1] = __fadd_rn(L[1], __fmul_rn(z4.y, b4.y));
                L[2] = __fadd_rn(L[2], __fmul_rn(z4.z, b4.z));
                L[3] = __fadd_rn(L[3], __fmul_rn(z4.w, b4.w));
                r[m8 + 0] = __fadd_rn(r[m8 + 0], __fmul_rn(b4.x, b4.x));
                r[m8 + 1] = __fadd_rn(r[m8 + 1], __fmul_rn(b4.y, b4.y));
                r[m8 + 2] = __fadd_rn(r[m8 + 2], __fmul_rn(b4.z, b4.z));
                r[m8 + 3] = __fadd_rn(r[m8 + 3], __fmul_rn(b4.w, b4.w));
                q[m8 + 0] = __fadd_rn(q[m8 + 0], __fmul_rn(z4.x, z4.x));
                q[m8 + 1] = __fadd_rn(q[m8 + 1], __fmul_rn(z4.y, z4.y));
                q[m8 + 2] = __fadd_rn(q[m8 + 2], __fmul_rn(z4.z, z4.z));
                q[m8 + 3] = __fadd_rn(q[m8 + 3], __fmul_rn(z4.w, z4.w));
            }
            const float dot = __fadd_rn(__fadd_rn(L[0], L[2]), __fadd_rn(L[1], L[3]));
            const float bqv = __fadd_rn(__fadd_rn(__fadd_rn(r[0], r[1]), __fadd_rn(r[2], r[3])),
                                        __fadd_rn(__fadd_rn(r[4], r[5]), __fadd_rn(r[6], r[7])));
            const float zqv = __fadd_rn(__fadd_rn(__fadd_rn(q[0], q[1]), __fadd_rn(q[2], q[3])),
                                        __fadd_rn(__fadd_rn(q[4], q[5]), __fadd_rn(q[6], q[7])));
            sv[t] = __fsub_rn(__fsub_rn(__fmul_rn(2.0f, dot), zqv), bqv);
        }
        __syncthreads();

        if (t < 64) {
            float s0 = sv[t]; int i0 = sel[t];
            float s1 = -FLT_MAX; int i1 = INT_MAX;
            if (t + 64 < CAND) { s1 = sv[t + 64]; i1 = sel[t + 64]; }

            for (int rd = 0; rd < KK; rd++) {
                float bs; int bn;
                if (s0 > s1 || (s0 == s1 && i0 < i1)) { bs = s0; bn = i0; }
                else                                  { bs = s1; bn = i1; }
                const float ms = bs; const int mn = bn;
                #pragma unroll
                for (int m = 1; m < 64; m <<= 1) {
                    float os = __shfl_xor(bs, m, 64);
                    int on = __shfl_xor(bn, m, 64);
                    if (os > bs || (os == bs && on < bn)) { bs = os; bn = on; }
                }
                if (bs == ms && bn == mn) {
                    if (i0 == mn) s0 = -FLT_MAX; else s1 = -FLT_MAX;
                }
                if (t == 0) {
                    const int o = row * KK + rd;
                    out[O_VE + o] = bs;            // bitwise np-fp32 score
                    out[O_IE + o] = (float)bn;
                    const int o3 = O_LT + o * 3;
                    out[o3 + 0] = transB[bn * 3 + 0];
                    out[o3 + 1] = transB[bn * 3 + 1];
                    out[o3 + 2] = transB[bn * 3 + 2];
                }
            }
        }
    }
}

// ---------------- launch ------------------------------------------------------------
extern "C" void kernel_launch(void* const* d_in, const int* in_sizes, int n_in,
                              void* d_out, int out_size, void* d_ws, size_t ws_size,
                              hipStream_t stream) {
    const float* zR = (const float*)d_in[0];
    const float* zT = (const float*)d_in[1];
    const float* bR = (const float*)d_in[2];
    const float* bT = (const float*)d_in[3];
    const float* rotB = (const float*)d_in[4];
    const float* transB = (const float*)d_in[5];
    float* out = (float*)d_out;

    // ws layout: bq[NN] floats | candI[2*BB*CAND] ints  (~2.2 MB total)
    float* bq = (float*)d_ws;
    int* candI = (int*)(bq + NN);

    k0_bq<<<(NN * 32) / 256, 256, 0, stream>>>(bT, bq);
    k1_score<<<dim3(NSLICE, BB / TILEB, 2), 256, 0, stream>>>(zR, zT, bR, bT, bq, candI);
    k2_final<<<dim3(BB, 2), 256, 0, stream>>>(zR, zT, bR, bT, rotB, transB, candI, out);
}

// Round 4
// 703.254 us; speedup vs baseline: 3.4565x; 3.4565x over previous
//
#include <hip/hip_runtime.h>
#include <cfloat>
#include <climits>
#include <math.h>

// Problem constants (fixed by reference)
#define BB 2048
#define NN 50000
#define DD 128
#define KK 20

#define NSLICE 10
#define NSL 5000        // NN / NSLICE
#define SL 12           // per-(row,slice) survivors
#define CAND (NSLICE*SL)  // 120 candidates per row per task
#define LL 12           // per-thread candidate list length
#define NIT 79          // ceil(5000/64) col-iterations per slice

// out layout (floats): vals_cos, ind_cos, labels_rot, vals_euc, ind_euc, labels_trans
#define O_VC 0
#define O_IC 40960
#define O_LR 81920
#define O_VE 122880
#define O_IE 163840
#define O_LT 204800

// ws layout (bytes)
#define WS_BQ    0
#define WS_CANDI 200000
#define WS_ZBF   2166080
#define WS_BBF   3214656
#define WS_NEED  28814656ULL

typedef short v8s __attribute__((ext_vector_type(8)));
typedef float v16f __attribute__((ext_vector_type(16)));

// ---------------- K0a: bq[n] = ||trans_book[n]||^2 (fp32, selection only) -----------
__global__ __launch_bounds__(256) void k0_bq(const float* __restrict__ Bt,
                                             float* __restrict__ bq) {
    int gid = blockIdx.x * 256 + threadIdx.x;
    int row = gid >> 5;
    int lane = threadIdx.x & 31;
    if (row < NN) {
        float4 v = *reinterpret_cast<const float4*>(Bt + (size_t)row * DD + lane * 4);
        float s = v.x * v.x + v.y * v.y + v.z * v.z + v.w * v.w;
        #pragma unroll
        for (int m = 1; m < 32; m <<= 1) s += __shfl_xor(s, m, 64);
        if (lane == 0) bq[row] = s;
    }
}

// ---------------- K0b: fp32 -> bf16 (RNE) conversion, 8 elems/thread ----------------
__device__ __forceinline__ unsigned int bf16rne(float f) {
    unsigned int x = __float_as_uint(f);
    return (x + 0x7FFFu + ((x >> 16) & 1u)) >> 16;
}
__global__ __launch_bounds__(256) void k_cvt(const float* __restrict__ src,
                                             unsigned int* __restrict__ dst, int n8) {
    int i = blockIdx.x * 256 + threadIdx.x;
    if (i < n8) {
        const float4* s = reinterpret_cast<const float4*>(src + (size_t)i * 8);
        float4 a = s[0], b = s[1];
        uint4 o;
        o.x = bf16rne(a.x) | (bf16rne(a.y) << 16);
        o.y = bf16rne(a.z) | (bf16rne(a.w) << 16);
        o.z = bf16rne(b.x) | (bf16rne(b.y) << 16);
        o.w = bf16rne(b.z) | (bf16rne(b.w) << 16);
        reinterpret_cast<uint4*>(dst)[i] = o;
    }
}

// ---------------- K1 (fast): bf16 MFMA scoring + per-(row,slice) top-SL -------------
// grid (NSLICE, 32, 2), block 256 (4 waves). Block: 64 rows x 5000-col slice.
// Per iter: waves compute a 64x64 score tile (each wave one 32x32 MFMA subtile,
// K=128 via 8x mfma_32x32x16_bf16), dump to LDS (swizzled), 256 readers keep
// per-thread top-12 over their (row, 16-col-class) stream -> shfl-merge of 4.
__global__ __launch_bounds__(256) void k1_mfma(
    const short* __restrict__ Zbf,   // [2][2048][128]
    const short* __restrict__ Bbf,   // [2][50000][128]
    const float* __restrict__ bq,
    int* __restrict__ candI)
{
    const int slice = blockIdx.x;
    const int tile  = blockIdx.y;
    const int task  = blockIdx.z;
    const short* __restrict__ Zk = Zbf + (size_t)task * BB * DD;
    const short* __restrict__ Bk = Bbf + (size_t)task * NN * DD;

    __shared__ float sbuf[4096];    // 4 waves x 1024 words = 16 KB

    const int t = threadIdx.x;
    const int w = t >> 6;
    const int lane = t & 63;
    const int hi = lane >> 5;
    const int nbase = slice * NSL;

    // ---- A fragments (32 rows per wave), persistent ----
    const int rloc = 32 * (w & 1) + (lane & 31);
    v8s a[8];
    {
        const short* zp = Zk + (size_t)(tile * 64 + rloc) * DD + 8 * hi;
        #pragma unroll
        for (int q = 0; q < 8; q++) a[q] = *reinterpret_cast<const v8s*>(zp + 16 * q);
    }
    const int cwave = 32 * (w >> 1);
    const int s4 = (lane >> 1) & 3;     // write swizzle

    // ---- reader role constants ----
    const int r = t >> 2;               // local row 0..63
    const int cg = t & 3;               // 16-col group
    const int r32 = r & 31;
    const int rhi = (r32 >> 2) & 1;
    const int qr = r32 >> 3;
    const int rlow = r32 & 3;
    const int w_r = ((r >> 5) & 1) | ((cg >> 1) << 1);
    const int lane0 = ((cg & 1) << 4) | (rhi << 5);
    const int wbase = (w_r << 10) | rlow;

    float ls[LL]; int li[LL];
    float lmin = -FLT_MAX; int mpos = 0;
    #pragma unroll
    for (int u = 0; u < LL; u++) { ls[u] = -FLT_MAX; li[u] = INT_MAX; }

    // ---- prefetch B for it=0 ----
    v8s b[8]; float bqv = 0.f;
    {
        int c = cwave + (lane & 31);
        if (c > NSL - 1) c = NSL - 1;
        const short* bp = Bk + (size_t)(nbase + c) * DD + 8 * hi;
        #pragma unroll
        for (int q = 0; q < 8; q++) b[q] = *reinterpret_cast<const v8s*>(bp + 16 * q);
        if (task) bqv = bq[nbase + c];
    }

    for (int it = 0; it < NIT; it++) {
        __syncthreads();   // scorebuf free (readers of it-1 done)

        v16f acc = {0.f,0.f,0.f,0.f, 0.f,0.f,0.f,0.f, 0.f,0.f,0.f,0.f, 0.f,0.f,0.f,0.f};
        #pragma unroll
        for (int q = 0; q < 8; q++)
            acc = __builtin_amdgcn_mfma_f32_32x32x16_bf16(a[q], b[q], acc, 0, 0, 0);

        // write scores (euc: fold s = 2*dot - bq[n] here; col uniform per lane)
        {
            float* wv = sbuf + ((w << 10) | (lane << 4));
            #pragma unroll
            for (int q = 0; q < 4; q++) {
                float4 v;
                v.x = acc[4 * q + 0]; v.y = acc[4 * q + 1];
                v.z = acc[4 * q + 2]; v.w = acc[4 * q + 3];
                if (task) {
                    v.x = 2.f * v.x - bqv; v.y = 2.f * v.y - bqv;
                    v.z = 2.f * v.z - bqv; v.w = 2.f * v.w - bqv;
                }
                *reinterpret_cast<float4*>(wv + ((q ^ s4) << 2)) = v;
            }
        }
        __syncthreads();

        // prefetch next iter's B (overlaps reader phase)
        if (it + 1 < NIT) {
            int c = (it + 1) * 64 + cwave + (lane & 31);
            if (c > NSL - 1) c = NSL - 1;
            const short* bp = Bk + (size_t)(nbase + c) * DD + 8 * hi;
            #pragma unroll
            for (int q = 0; q < 8; q++) b[q] = *reinterpret_cast<const v8s*>(bp + 16 * q);
            if (task) bqv = bq[nbase + c];
        }

        // reader: 16 scores of (row r, cols cg*16..+15)
        const int lim = NSL - it * 64;           // >=64 except last iter (=8)
        const int nb = nbase + it * 64 + cg * 16;
        #pragma unroll
        for (int j = 0; j < 16; j++) {
            const int c = cg * 16 + j;
            if (c < lim) {
                const int lnj = lane0 + j;
                const int q2 = qr ^ ((lnj >> 1) & 3);
                const float s = sbuf[wbase + (lnj << 4) + (q2 << 2)];
                if (s > lmin) {
                    const int n = nb + j;
                    #pragma unroll
                    for (int u = 0; u < LL; u++)
                        if (u == mpos) { ls[u] = s; li[u] = n; }
                    float m = ls[0]; int mp = 0;
                    #pragma unroll
                    for (int u = 1; u < LL; u++)
                        if (ls[u] < m) { m = ls[u]; mp = u; }
                    lmin = m; mpos = mp;
                }
            }
        }
    }

    // ---- merge 4 threads/row (aligned 4-lane groups), write top-SL indices ----
    {
        const int row = tile * 64 + r;
        const int base = ((task * BB + row) * NSLICE + slice) * SL;
        for (int rd = 0; rd < SL; rd++) {
            float bs = -FLT_MAX; int bn = INT_MAX; int bq_ = -1;
            #pragma unroll
            for (int u = 0; u < LL; u++)
                if (ls[u] > bs || (ls[u] == bs && li[u] < bn)) {
                    bs = ls[u]; bn = li[u]; bq_ = u;
                }
            const float ms = bs; const int mn = bn;
            #pragma unroll
            for (int m = 1; m < 4; m <<= 1) {
                float os = __shfl_xor(bs, m, 64);
                int on = __shfl_xor(bn, m, 64);
                if (os > bs || (os == bs && on < bn)) { bs = os; bn = on; }
            }
            if (bs == ms && bn == mn) {
                #pragma unroll
                for (int u = 0; u < LL; u++) if (u == bq_) ls[u] = -FLT_MAX;
            }
            if (cg == 0) candI[base + rd] = bn;
        }
    }
}

// ---------------- K1 (fallback, ws too small): R3's fp32 scalar version -------------
#define NCF 40
#define NCHUNKF 125
#define GGF 8
#define NTF 5
__global__ __launch_bounds__(256) void k1_fallback(
    const float* __restrict__ Zr, const float* __restrict__ Zt,
    const float* __restrict__ Br, const float* __restrict__ Bt,
    const float* __restrict__ bq,
    int* __restrict__ candI)
{
    const int slice = blockIdx.x;
    const int tile  = blockIdx.y;
    const int task  = blockIdx.z;
    const float* __restrict__ Z  = task ? Zt : Zr;
    const float* __restrict__ Bk = task ? Bt : Br;

    __shared__ __align__(16) float z_lds[64][132];
    __shared__ __align__(16) float b_lds[NCF][132];
    __shared__ float bq_lds[NCF];

    const int t = threadIdx.x;
    const int r0 = tile * 64;
    const int nbase = slice * NSL;

    #pragma unroll
    for (int i = 0; i < 8; i++) {
        int idx = t + i * 256;
        int r = idx >> 5, kq = idx & 31;
        float4 v = *reinterpret_cast<const float4*>(Z + (size_t)(r0 + r) * DD + kq * 4);
        *reinterpret_cast<float4*>(&z_lds[r][kq * 4]) = v;
    }

    const int rp = t >> 3;
    const int g  = t & 7;
    const int rA = rp * 2;

    float ls[2][LL]; int li[2][LL];
    float lmin[2]; int mpos[2];
    #pragma unroll
    for (int rr = 0; rr < 2; rr++) {
        #pragma unroll
        for (int u = 0; u < LL; u++) { ls[rr][u] = -FLT_MAX; li[rr][u] = INT_MAX; }
        lmin[rr] = -FLT_MAX; mpos[rr] = 0;
    }
    const bool is_euc = (task != 0);

    for (int c = 0; c < NCHUNKF; c++) {
        const int n0 = nbase + c * NCF;
        __syncthreads();
        #pragma unroll
        for (int i = 0; i < 5; i++) {
            int idx = t + i * 256;
            int nl = idx >> 5, kq = idx & 31;
            float4 v = *reinterpret_cast<const float4*>(Bk + (size_t)(n0 + nl) * DD + kq * 4);
            *reinterpret_cast<float4*>(&b_lds[nl][kq * 4]) = v;
        }
        if (t < NCF) bq_lds[t] = bq[n0 + t];
        __syncthreads();

        float acc[2][NTF];
        #pragma unroll
        for (int rr = 0; rr < 2; rr++)
            #pragma unroll
            for (int j = 0; j < NTF; j++) acc[rr][j] = 0.f;

        for (int kq = 0; kq < 32; kq++) {
            float4 za = *reinterpret_cast<const float4*>(&z_lds[rA][kq * 4]);
            float4 zb = *reinterpret_cast<const float4*>(&z_lds[rA + 1][kq * 4]);
            #pragma unroll
            for (int j = 0; j < NTF; j++) {
                float4 b4 = *reinterpret_cast<const float4*>(&b_lds[g + (j << 3)][kq * 4]);
                acc[0][j] += za.x * b4.x + za.y * b4.y + za.z * b4.z + za.w * b4.w;
                acc[1][j] += zb.x * b4.x + zb.y * b4.y + zb.z * b4.z + zb.w * b4.w;
            }
        }

        #pragma unroll
        for (int j = 0; j < NTF; j++) {
            const int nl = g + (j << 3);
            const float bqv = bq_lds[nl];
            const int n = n0 + nl;
            #pragma unroll
            for (int rr = 0; rr < 2; rr++) {
                float s = is_euc ? (2.f * acc[rr][j] - bqv) : acc[rr][j];
                if (s > lmin[rr]) {
                    #pragma unroll
                    for (int u = 0; u < LL; u++)
                        if (u == mpos[rr]) { ls[rr][u] = s; li[rr][u] = n; }
                    float m = ls[rr][0]; int mp = 0;
                    #pragma unroll
                    for (int u = 1; u < LL; u++)
                        if (ls[rr][u] < m) { m = ls[rr][u]; mp = u; }
                    lmin[rr] = m; mpos[rr] = mp;
                }
            }
        }
    }

    #pragma unroll
    for (int rr = 0; rr < 2; rr++) {
        const int row = r0 + rA + rr;
        const int base = ((task * BB + row) * NSLICE + slice) * SL;
        for (int rd = 0; rd < SL; rd++) {
            float bs = -FLT_MAX; int bn = INT_MAX; int bq_ = -1;
            #pragma unroll
            for (int u = 0; u < LL; u++)
                if (ls[rr][u] > bs || (ls[rr][u] == bs && li[rr][u] < bn)) {
                    bs = ls[rr][u]; bn = li[rr][u]; bq_ = u;
                }
            const float ms = bs; const int mn = bn;
            #pragma unroll
            for (int m = 1; m < GGF; m <<= 1) {
                float os = __shfl_xor(bs, m, 64);
                int on = __shfl_xor(bn, m, 64);
                if (os > bs || (os == bs && on < bn)) { bs = os; bn = on; }
            }
            if (bs == ms && bn == mn) {
                #pragma unroll
                for (int u = 0; u < LL; u++) if (u == bq_) ls[rr][u] = -FLT_MAX;
            }
            if (g == 0) candI[base + rd] = bn;
        }
    }
}

// ---------------- K2: final ranking + gather (unchanged from R3 — passes) -----------
__global__ __launch_bounds__(256) void k2_final(
    const float* __restrict__ Zr, const float* __restrict__ Zt,
    const float* __restrict__ Br, const float* __restrict__ Bt,
    const float* __restrict__ rotB, const float* __restrict__ transB,
    const int* __restrict__ candI,
    float* __restrict__ out)
{
    const int row = blockIdx.x;
    const int task = blockIdx.y;
    const int t = threadIdx.x;
    const float* __restrict__ Z  = task ? Zt : Zr;
    const float* __restrict__ Bk = task ? Bt : Br;

    __shared__ __align__(16) float zrow[DD];
    __shared__ int sel[CAND];
    __shared__ double dotp[CAND * 8];
    __shared__ double sval[KK];
    __shared__ int sidx[KK];
    __shared__ float sv[CAND];

    if (t < DD) zrow[t] = Z[(size_t)row * DD + t];
    if (t < CAND) sel[t] = candI[((size_t)task * BB + row) * CAND + t];
    __syncthreads();

    if (task == 0) {
        #pragma unroll
        for (int it = 0; it < 4; it++) {
            int idx = t + it * 256;
            if (idx < CAND * 8) {
                int cnd = idx >> 3, part = idx & 7;
                int n = sel[cnd];
                const float* brow = Bk + (size_t)n * DD + part * 16;
                double dp = 0.0;
                #pragma unroll
                for (int q = 0; q < 4; q++) {
                    float4 b4 = *reinterpret_cast<const float4*>(brow + q * 4);
                    const int k = part * 16 + q * 4;
                    dp += (double)zrow[k + 0] * (double)b4.x + (double)zrow[k + 1] * (double)b4.y
                        + (double)zrow[k + 2] * (double)b4.z + (double)zrow[k + 3] * (double)b4.w;
                }
                dotp[idx] = dp;
            }
        }
        __syncthreads();

        if (t < 64) {
            double zq = (double)zrow[t] * (double)zrow[t]
                      + (double)zrow[t + 64] * (double)zrow[t + 64];
            #pragma unroll
            for (int m = 1; m < 64; m <<= 1) zq += __shfl_xor(zq, m, 64);

            double s0, s1 = -DBL_MAX; int i0, i1 = INT_MAX;
            {
                double dot = 0.0;
                #pragma unroll
                for (int p = 0; p < 8; p++) dot += dotp[t * 8 + p];
                i0 = sel[t]; s0 = dot;
            }
            if (t + 64 < CAND) {
                double dot = 0.0;
                #pragma unroll
                for (int p = 0; p < 8; p++) dot += dotp[(t + 64) * 8 + p];
                i1 = sel[t + 64]; s1 = dot;
            }

            for (int rd = 0; rd < KK; rd++) {
                double bs; int bn;
                if (s0 > s1 || (s0 == s1 && i0 < i1)) { bs = s0; bn = i0; }
                else                                  { bs = s1; bn = i1; }
                const double ms = bs; const int mn = bn;
                #pragma unroll
                for (int m = 1; m < 64; m <<= 1) {
                    double os = __shfl_xor(bs, m, 64);
                    int on = __shfl_xor(bn, m, 64);
                    if (os > bs || (os == bs && on < bn)) { bs = os; bn = on; }
                }
                if (bs == ms && bn == mn) {
                    if (i0 == mn) s0 = -DBL_MAX; else s1 = -DBL_MAX;
                }
                if (t == 0) { sval[rd] = bs; sidx[rd] = bn; }
            }
            if (t == 0) dotp[0] = zq;
        }
        __syncthreads();

        if (t < KK) {
            const double zq = dotp[0];
            const int n = sidx[t];
            const int o = row * KK + t;
            out[O_VC + o] = (float)(sval[t] / sqrt(zq));
            out[O_IC + o] = (float)n;
            out[O_LR + o] = rotB[n];
        }
    } else {
        // euc: bit-exact numpy-fp32 emulation (verified in R3)
        if (t < CAND) {
            const int n = sel[t];
            const float* brow = Bk + (size_t)n * DD;
            float L[4], r[8], q[8];
            #pragma unroll
            for (int u = 0; u < 4; u++) L[u] = 0.f;
            #pragma unroll
            for (int u = 0; u < 8; u++) { r[u] = 0.f; q[u] = 0.f; }
            #pragma unroll
            for (int c4 = 0; c4 < 32; c4++) {
                float4 b4 = *reinterpret_cast<const float4*>(brow + c4 * 4);
                float4 z4 = *reinterpret_cast<const float4*>(&zrow[c4 * 4]);
                const int m8 = (c4 & 1) * 4;
                L[0] = __fadd_rn(L[0], __fmul_rn(z4.x, b4.x));
                L[1] = __fadd_rn(L[1], __fmul_rn(z4.y, b4.y));
                L[2] = __fadd_rn(L[2], __fmul_rn(z4.z, b4.z));
                L[3] = __fadd_rn(L[3], __fmul_rn(z4.w, b4.w));
                r[m8 + 0] = __fadd_rn(r[m8 + 0], __fmul_rn(b4.x, b4.x));
                r[m8 + 1] = __fadd_rn(r[m8 + 1], __fmul_rn(b4.y, b4.y));
                r[m8 + 2] = __fadd_rn(r[m8 + 2], __fmul_rn(b4.z, b4.z));
                r[m8 + 3] = __fadd_rn(r[m8 + 3], __fmul_rn(b4.w, b4.w));
                q[m8 + 0] = __fadd_rn(q[m8 + 0], __fmul_rn(z4.x, z4.x));
                q[m8 + 1] = __fadd_rn(q[m8 + 1], __fmul_rn(z4.y, z4.y));
                q[m8 + 2] = __fadd_rn(q[m8 + 2], __fmul_rn(z4.z, z4.z));
                q[m8 + 3] = __fadd_rn(q[m8 + 3], __fmul_rn(z4.w, z4.w));
            }
            const float dot = __fadd_rn(__fadd_rn(L[0], L[2]), __fadd_rn(L[1], L[3]));
            const float bqv = __fadd_rn(__fadd_rn(__fadd_rn(r[0], r[1]), __fadd_rn(r[2], r[3])),
                                        __fadd_rn(__fadd_rn(r[4], r[5]), __fadd_rn(r[6], r[7])));
            const float zqv = __fadd_rn(__fadd_rn(__fadd_rn(q[0], q[1]), __fadd_rn(q[2], q[3])),
                                        __fadd_rn(__fadd_rn(q[4], q[5]), __fadd_rn(q[6], q[7])));
            sv[t] = __fsub_rn(__fsub_rn(__fmul_rn(2.0f, dot), zqv), bqv);
        }
        __syncthreads();

        if (t < 64) {
            float s0 = sv[t]; int i0 = sel[t];
            float s1 = -FLT_MAX; int i1 = INT_MAX;
            if (t + 64 < CAND) { s1 = sv[t + 64]; i1 = sel[t + 64]; }

            for (int rd = 0; rd < KK; rd++) {
                float bs; int bn;
                if (s0 > s1 || (s0 == s1 && i0 < i1)) { bs = s0; bn = i0; }
                else                                  { bs = s1; bn = i1; }
                const float ms = bs; const int mn = bn;
                #pragma unroll
                for (int m = 1; m < 64; m <<= 1) {
                    float os = __shfl_xor(bs, m, 64);
                    int on = __shfl_xor(bn, m, 64);
                    if (os > bs || (os == bs && on < bn)) { bs = os; bn = on; }
                }
                if (bs == ms && bn == mn) {
                    if (i0 == mn) s0 = -FLT_MAX; else s1 = -FLT_MAX;
                }
                if (t == 0) {
                    const int o = row * KK + rd;
                    out[O_VE + o] = bs;
                    out[O_IE + o] = (float)bn;
                    const int o3 = O_LT + o * 3;
                    out[o3 + 0] = transB[bn * 3 + 0];
                    out[o3 + 1] = transB[bn * 3 + 1];
                    out[o3 + 2] = transB[bn * 3 + 2];
                }
            }
        }
    }
}

// ---------------- launch ------------------------------------------------------------
extern "C" void kernel_launch(void* const* d_in, const int* in_sizes, int n_in,
                              void* d_out, int out_size, void* d_ws, size_t ws_size,
                              hipStream_t stream) {
    const float* zR = (const float*)d_in[0];
    const float* zT = (const float*)d_in[1];
    const float* bR = (const float*)d_in[2];
    const float* bT = (const float*)d_in[3];
    const float* rotB = (const float*)d_in[4];
    const float* transB = (const float*)d_in[5];
    float* out = (float*)d_out;

    char* ws = (char*)d_ws;
    float* bq = (float*)(ws + WS_BQ);
    int* candI = (int*)(ws + WS_CANDI);

    k0_bq<<<(NN * 32) / 256, 256, 0, stream>>>(bT, bq);

    if (ws_size >= WS_NEED) {
        short* Zbf = (short*)(ws + WS_ZBF);
        short* Bbf = (short*)(ws + WS_BBF);
        unsigned int* ZbfU = (unsigned int*)Zbf;
        unsigned int* BbfU = (unsigned int*)Bbf;
        const int z8 = BB * DD / 8;     // 32768
        const int b8 = NN * DD / 8;     // 800000
        k_cvt<<<(z8 + 255) / 256, 256, 0, stream>>>(zR, ZbfU, z8);
        k_cvt<<<(z8 + 255) / 256, 256, 0, stream>>>(zT, ZbfU + (size_t)BB * DD / 2, z8);
        k_cvt<<<(b8 + 255) / 256, 256, 0, stream>>>(bR, BbfU, b8);
        k_cvt<<<(b8 + 255) / 256, 256, 0, stream>>>(bT, BbfU + (size_t)NN * DD / 2, b8);
        k1_mfma<<<dim3(NSLICE, BB / 64, 2), 256, 0, stream>>>(Zbf, Bbf, bq, candI);
    } else {
        k1_fallback<<<dim3(NSLICE, BB / 64, 2), 256, 0, stream>>>(zR, zT, bR, bT, bq, candI);
    }

    k2_final<<<dim3(BB, 2), 256, 0, stream>>>(zR, zT, bR, bT, rotB, transB, candI, out);
}

// Round 5
// 446.610 us; speedup vs baseline: 5.4428x; 1.5746x over previous
//
#include <hip/hip_runtime.h>
#include <cfloat>
#include <climits>
#include <math.h>

// Problem constants
#define BB 2048
#define NN 50000
#define DD 128
#define KK 20

// K1 selection geometry
#define NSLICE 16
#define NSL 3125          // NN / NSLICE (exact)
#define NTILE 98          // ceil(NSL/32); tile 97 partial (21 valid entries)
#define LK 8              // per-lane sorted key slots
#define SLC 16            // per (row,slice) stored candidates (2 lanes x LK)
#define CAND 256          // NSLICE * SLC per row per task

// out layout (floats): vals_cos, ind_cos, labels_rot, vals_euc, ind_euc, labels_trans
#define O_VC 0
#define O_IC 40960
#define O_LR 81920
#define O_VE 122880
#define O_IE 163840
#define O_LT 204800

// ws layout (bytes): Bbf 25.6MB | bq2 200KB | candU 2.1MB = 27.90MB (<=28.81MB proven in R4)
#define WS_BBF   0
#define WS_BQ2   25600000
#define WS_CAND  25800000

typedef short v8s __attribute__((ext_vector_type(8)));
typedef float v16f __attribute__((ext_vector_type(16)));

union U4V8 { uint4 u; v8s v; };

__device__ __forceinline__ unsigned int bf16rne(float f) {
    unsigned int x = __float_as_uint(f);
    return (x + 0x7FFFu + ((x >> 16) & 1u)) >> 16;
}
// monotone fp32 -> u32 (total order), then truncated to hi-16 in the key
__device__ __forceinline__ unsigned int sortkey(float s) {
    unsigned int b = __float_as_uint(s);
    unsigned int m = ((unsigned int)((int)b >> 31)) >> 1;   // 0 or 0x7FFFFFFF
    return b ^ (0x80000000u | m);
}

// ---------------- K0: build bf16 book (cos: b, euc: 2b) + packed -bq (hi/lo bf16) ----
// 32 lanes per entry; 2 entries per wave; 8 entries per block.
__global__ __launch_bounds__(256) void k_cvt2(const float* __restrict__ bR,
                                              const float* __restrict__ bT,
                                              unsigned int* __restrict__ Bbf,
                                              unsigned int* __restrict__ bq2)
{
    const int t = threadIdx.x;
    const int job = (blockIdx.x * 256 + t) >> 5;     // 0..99999
    const int l = t & 31;
    const int task = job >= NN;
    const int e = job - task * NN;

    const float* src = (task ? bT : bR) + (size_t)e * DD + l * 4;
    float4 v = *reinterpret_cast<const float4*>(src);
    float sq = v.x * v.x + v.y * v.y + v.z * v.z + v.w * v.w;   // from ORIGINAL b
    const float sc = task ? 2.f : 1.f;
    uint2 o;
    o.x = bf16rne(v.x * sc) | (bf16rne(v.y * sc) << 16);
    o.y = bf16rne(v.z * sc) | (bf16rne(v.w * sc) << 16);
    reinterpret_cast<uint2*>(Bbf)[(size_t)(task * NN + e) * 32 + l] = o;

    if (task) {
        #pragma unroll
        for (int m = 1; m < 32; m <<= 1) sq += __shfl_xor(sq, m, 64);  // stays in 32-group
        if (l == 0) {
            unsigned int hi = bf16rne(sq);
            float fhi = __uint_as_float(hi << 16);
            unsigned int lo = bf16rne(sq - fhi);
            bq2[e] = (hi ^ 0x8000u) | ((lo ^ 0x8000u) << 16);   // packed (-bq_hi, -bq_lo)
        }
    }
}

// ---------------- K1: swapped-operand MFMA scoring + in-register branchless top-8 ----
// One wave per (slice, rowgroup-of-32, task). A = book entries (m), B = z rows (n).
// C layout: n = lane&31 (z-row per lane), m = (reg&3)+8*(reg>>2)+4*(lane>>5).
// No LDS, no barriers. Key = sortkey(score)&0xFFFF0000 | n (n<50000 fits 16 bits;
// quantization 0.4% << selection margins; K2 re-ranks exactly).
__global__ __launch_bounds__(64) void k1_sel(
    const float* __restrict__ zR, const float* __restrict__ zT,
    const unsigned int* __restrict__ Bbf,
    const unsigned int* __restrict__ bq2,
    uint4* __restrict__ candU)
{
    const int slice = blockIdx.x;       // 0..15  (slice%8 -> XCD L2 locality)
    const int rg    = blockIdx.y;       // 0..63
    const int task  = blockIdx.z;
    const int lane  = threadIdx.x;
    const int col   = lane & 31;
    const int h     = lane >> 5;

    // ---- persistent z-frags (B operand): row = rg*32+col, k = 16q+8h..+8 ----
    const float* zp = (task ? zT : zR) + (size_t)(rg * 32 + col) * DD;
    v8s zf[9];
    #pragma unroll
    for (int q = 0; q < 8; q++) {
        float4 u0 = *reinterpret_cast<const float4*>(zp + q * 16 + h * 8);
        float4 u1 = *reinterpret_cast<const float4*>(zp + q * 16 + h * 8 + 4);
        U4V8 c;
        c.u.x = bf16rne(u0.x) | (bf16rne(u0.y) << 16);
        c.u.y = bf16rne(u0.z) | (bf16rne(u0.w) << 16);
        c.u.z = bf16rne(u1.x) | (bf16rne(u1.y) << 16);
        c.u.w = bf16rne(u1.z) | (bf16rne(u1.w) << 16);
        zf[q] = c.v;
    }
    {   // 9th step: k=128,129 -> 1.0,1.0 (h=0); zeros (h=1)
        U4V8 c; c.u = make_uint4(h == 0 ? 0x3F803F80u : 0u, 0u, 0u, 0u);
        zf[8] = c.v;
    }

    unsigned int key[LK];
    #pragma unroll
    for (int u = 0; u < LK; u++) key[u] = 0u;

    const int nbase0 = slice * NSL;
    const unsigned int* bp = Bbf + (size_t)task * NN * 64;   // u32 units, 64/entry

    for (int tile = 0; tile < NTILE; tile++) {
        const bool tail = (tile == NTILE - 1);
        int e = nbase0 + tile * 32 + col;
        if (tail) e = min(e, nbase0 + NSL - 1);                 // clamp loads
        const unsigned int* ep = bp + (size_t)e * 64 + h * 4;

        v16f acc = {0.f,0.f,0.f,0.f, 0.f,0.f,0.f,0.f, 0.f,0.f,0.f,0.f, 0.f,0.f,0.f,0.f};
        #pragma unroll
        for (int q = 0; q < 8; q++) {
            U4V8 a; a.u = *reinterpret_cast<const uint4*>(ep + q * 8);
            acc = __builtin_amdgcn_mfma_f32_32x32x16_bf16(a.v, zf[q], acc, 0, 0, 0);
        }
        if (task) {  // 9th step folds -bq (h=0 lanes carry [-bq_hi,-bq_lo,0..])
            unsigned int bqp = bq2[e];
            U4V8 a; a.u = make_uint4(h == 0 ? bqp : 0u, 0u, 0u, 0u);
            acc = __builtin_amdgcn_mfma_f32_32x32x16_bf16(a.v, zf[8], acc, 0, 0, 0);
        }

        const int nb = nbase0 + tile * 32 + 4 * h;
        #pragma unroll
        for (int r = 0; r < 16; r++) {
            const int pat = (r & 3) + 8 * (r >> 2);             // + 4h in nb
            const int n = nb + pat;
            unsigned int k = (sortkey(acc[r]) & 0xFFFF0000u) | (unsigned int)n;
            if (tail && (tile * 32 + pat + 4 * h >= NSL)) k = 0u;  // mask invalid
            // branchless sorted insert (ascending; key[0] = current min)
            #pragma unroll
            for (int u = 0; u < LK - 1; u++) {
                unsigned int mx = max(k, key[u]);
                key[u] = min(key[u + 1], mx);
            }
            key[LK - 1] = max(k, key[LK - 1]);
        }
    }

    // ---- writeout: 8 entry-indices per lane -> 16B store; 16 per (row,slice) ----
    uint4 o;
    o.x = (key[0] & 0xFFFFu) | ((key[1] & 0xFFFFu) << 16);
    o.y = (key[2] & 0xFFFFu) | ((key[3] & 0xFFFFu) << 16);
    o.z = (key[4] & 0xFFFFu) | ((key[5] & 0xFFFFu) << 16);
    o.w = (key[6] & 0xFFFFu) | ((key[7] & 0xFFFFu) << 16);
    const int row = rg * 32 + col;
    candU[((size_t)(task * BB + row) * NSLICE + slice) * 2 + h] = o;
}

// ---------------- K2: exact final ranking + gather (R3-verified logic, CAND=256) ----
__global__ __launch_bounds__(256) void k2_final(
    const float* __restrict__ Zr, const float* __restrict__ Zt,
    const float* __restrict__ Br, const float* __restrict__ Bt,
    const float* __restrict__ rotB, const float* __restrict__ transB,
    const unsigned short* __restrict__ candU16,
    float* __restrict__ out)
{
    const int row = blockIdx.x;
    const int task = blockIdx.y;
    const int t = threadIdx.x;
    const float* __restrict__ Z  = task ? Zt : Zr;
    const float* __restrict__ Bk = task ? Bt : Br;

    __shared__ __align__(16) float zrow[DD];
    __shared__ int sel[CAND];
    __shared__ double dotp[CAND * 8];
    __shared__ double sval[KK];
    __shared__ int sidx[KK];
    __shared__ float sv[CAND];

    if (t < DD) zrow[t] = Z[(size_t)row * DD + t];
    sel[t] = (int)candU16[((size_t)task * BB + row) * CAND + t];
    __syncthreads();

    if (task == 0) {
        // ---- cos: exact fp64 rescore + top-20 ----
        #pragma unroll
        for (int it = 0; it < 8; it++) {
            int idx = t + it * 256;
            int cnd = idx >> 3, part = idx & 7;
            int n = sel[cnd];
            const float* brow = Bk + (size_t)n * DD + part * 16;
            double dp = 0.0;
            #pragma unroll
            for (int q = 0; q < 4; q++) {
                float4 b4 = *reinterpret_cast<const float4*>(brow + q * 4);
                const int k = part * 16 + q * 4;
                dp += (double)zrow[k + 0] * (double)b4.x + (double)zrow[k + 1] * (double)b4.y
                    + (double)zrow[k + 2] * (double)b4.z + (double)zrow[k + 3] * (double)b4.w;
            }
            dotp[idx] = dp;
        }
        __syncthreads();

        if (t < 64) {
            double zq = (double)zrow[t] * (double)zrow[t]
                      + (double)zrow[t + 64] * (double)zrow[t + 64];
            #pragma unroll
            for (int m = 1; m < 64; m <<= 1) zq += __shfl_xor(zq, m, 64);

            double s[4]; int ix[4];
            #pragma unroll
            for (int j = 0; j < 4; j++) {
                const int c = t + 64 * j;
                double dot = 0.0;
                #pragma unroll
                for (int p = 0; p < 8; p++) dot += dotp[c * 8 + p];
                s[j] = dot; ix[j] = sel[c];
            }

            for (int rd = 0; rd < KK; rd++) {
                double bs = s[0]; int bn = ix[0];
                #pragma unroll
                for (int j = 1; j < 4; j++)
                    if (s[j] > bs || (s[j] == bs && ix[j] < bn)) { bs = s[j]; bn = ix[j]; }
                #pragma unroll
                for (int m = 1; m < 64; m <<= 1) {
                    double os = __shfl_xor(bs, m, 64);
                    int on = __shfl_xor(bn, m, 64);
                    if (os > bs || (os == bs && on < bn)) { bs = os; bn = on; }
                }
                #pragma unroll
                for (int j = 0; j < 4; j++) if (ix[j] == bn) s[j] = -DBL_MAX;  // pop (n unique)
                if (t == 0) { sval[rd] = bs; sidx[rd] = bn; }
            }
            if (t == 0) dotp[0] = zq;
        }
        __syncthreads();

        if (t < KK) {
            const double zq = dotp[0];
            const int n = sidx[t];
            const int o = row * KK + t;
            out[O_VC + o] = (float)(sval[t] / sqrt(zq));
            out[O_IC + o] = (float)n;
            out[O_LR + o] = rotB[n];
        }
    } else {
        // ---- euc: bit-exact numpy-fp32 emulation (verified R3) ----
        {
            const int n = sel[t];
            const float* brow = Bk + (size_t)n * DD;
            float L[4], r[8], q[8];
            #pragma unroll
            for (int u = 0; u < 4; u++) L[u] = 0.f;
            #pragma unroll
            for (int u = 0; u < 8; u++) { r[u] = 0.f; q[u] = 0.f; }
            #pragma unroll
            for (int c4 = 0; c4 < 32; c4++) {
                float4 b4 = *reinterpret_cast<const float4*>(brow + c4 * 4);
                float4 z4 = *reinterpret_cast<const float4*>(&zrow[c4 * 4]);
                const int m8 = (c4 & 1) * 4;
                L[0] = __fadd_rn(L[0], __fmul_rn(z4.x, b4.x));
                L[1] = __fadd_rn(L[1], __fmul_rn(z4.y, b4.y));
                L[2] = __fadd_rn(L[2], __fmul_rn(z4.z, b4.z));
                L[3] = __fadd_rn(L[3], __fmul_rn(z4.w, b4.w));
                r[m8 + 0] = __fadd_rn(r[m8 + 0], __fmul_rn(b4.x, b4.x));
                r[m8 + 1] = __fadd_rn(r[m8 + 1], __fmul_rn(b4.y, b4.y));
                r[m8 + 2] = __fadd_rn(r[m8 + 2], __fmul_rn(b4.z, b4.z));
                r[m8 + 3] = __fadd_rn(r[m8 + 3], __fmul_rn(b4.w, b4.w));
                q[m8 + 0] = __fadd_rn(q[m8 + 0], __fmul_rn(z4.x, z4.x));
                q[m8 + 1] = __fadd_rn(q[m8 + 1], __fmul_rn(z4.y, z4.y));
                q[m8 + 2] = __fadd_rn(q[m8 + 2], __fmul_rn(z4.z, z4.z));
                q[m8 + 3] = __fadd_rn(q[m8 + 3], __fmul_rn(z4.w, z4.w));
            }
            const float dot = __fadd_rn(__fadd_rn(L[0], L[2]), __fadd_rn(L[1], L[3]));
            const float bqv = __fadd_rn(__fadd_rn(__fadd_rn(r[0], r[1]), __fadd_rn(r[2], r[3])),
                                        __fadd_rn(__fadd_rn(r[4], r[5]), __fadd_rn(r[6], r[7])));
            const float zqv = __fadd_rn(__fadd_rn(__fadd_rn(q[0], q[1]), __fadd_rn(q[2], q[3])),
                                        __fadd_rn(__fadd_rn(q[4], q[5]), __fadd_rn(q[6], q[7])));
            sv[t] = __fsub_rn(__fsub_rn(__fmul_rn(2.0f, dot), zqv), bqv);
        }
        __syncthreads();

        if (t < 64) {
            float s[4]; int ix[4];
            #pragma unroll
            for (int j = 0; j < 4; j++) { s[j] = sv[t + 64 * j]; ix[j] = sel[t + 64 * j]; }

            for (int rd = 0; rd < KK; rd++) {
                float bs = s[0]; int bn = ix[0];
                #pragma unroll
                for (int j = 1; j < 4; j++)
                    if (s[j] > bs || (s[j] == bs && ix[j] < bn)) { bs = s[j]; bn = ix[j]; }
                #pragma unroll
                for (int m = 1; m < 64; m <<= 1) {
                    float os = __shfl_xor(bs, m, 64);
                    int on = __shfl_xor(bn, m, 64);
                    if (os > bs || (os == bs && on < bn)) { bs = os; bn = on; }
                }
                #pragma unroll
                for (int j = 0; j < 4; j++) if (ix[j] == bn) s[j] = -FLT_MAX;
                if (t == 0) {
                    const int o = row * KK + rd;
                    out[O_VE + o] = bs;
                    out[O_IE + o] = (float)bn;
                    const int o3 = O_LT + o * 3;
                    out[o3 + 0] = transB[bn * 3 + 0];
                    out[o3 + 1] = transB[bn * 3 + 1];
                    out[o3 + 2] = transB[bn * 3 + 2];
                }
            }
        }
    }
}

// ---------------- launch ------------------------------------------------------------
extern "C" void kernel_launch(void* const* d_in, const int* in_sizes, int n_in,
                              void* d_out, int out_size, void* d_ws, size_t ws_size,
                              hipStream_t stream) {
    const float* zR = (const float*)d_in[0];
    const float* zT = (const float*)d_in[1];
    const float* bR = (const float*)d_in[2];
    const float* bT = (const float*)d_in[3];
    const float* rotB = (const float*)d_in[4];
    const float* transB = (const float*)d_in[5];
    float* out = (float*)d_out;

    char* ws = (char*)d_ws;
    unsigned int* Bbf = (unsigned int*)(ws + WS_BBF);
    unsigned int* bq2 = (unsigned int*)(ws + WS_BQ2);
    uint4* candU = (uint4*)(ws + WS_CAND);

    k_cvt2<<<12500, 256, 0, stream>>>(bR, bT, Bbf, bq2);
    k1_sel<<<dim3(NSLICE, 64, 2), 64, 0, stream>>>(zR, zT, Bbf, bq2, candU);
    k2_final<<<dim3(BB, 2), 256, 0, stream>>>(zR, zT, bR, bT, rotB, transB,
                                              (const unsigned short*)candU, out);
}